// Round 9
// baseline (212.307 us; speedup 1.0000x reference)
//
#include <hip/hip_runtime.h>
#include <hip/hip_bf16.h>
#include <math.h>

#define N_NODES 40000
#define N_EDGES 640000
#define ET (N_EDGES + N_NODES)   // 680000 total edges incl. self-loops
#define SCAN_BLOCKS 40
#define SCAN_CHUNK 1000          // 40 * 1000 = 40000

__device__ __forceinline__ float wave_red_sum(float v) {
#pragma unroll
  for (int m = 32; m >= 1; m >>= 1) v += __shfl_xor(v, m, 64);
  return v;
}
__device__ __forceinline__ int wave_red_sum_i(int v) {
#pragma unroll
  for (int m = 32; m >= 1; m >>= 1) v += __shfl_xor(v, m, 64);
  return v;
}
__device__ __forceinline__ float half_red_sum(float v) {
#pragma unroll
  for (int m = 16; m >= 1; m >>= 1) v += __shfl_xor(v, m, 64);
  return v;
}

// ---------------- CSR build ----------------
// hist also records each edge's arrival rank within its dst bucket -> no atomic in k_fill
__global__ void k_hist(const int* __restrict__ ei, int* __restrict__ deg,
                       int* __restrict__ erank) {
  int i = blockIdx.x * blockDim.x + threadIdx.x;
  if (i >= ET) return;
  int d = (i < N_EDGES) ? ei[N_EDGES + i] : (i - N_EDGES);
  erank[i] = atomicAdd(&deg[d], 1);
}

// hierarchical scan, stage A: per-block sums of 1000-element chunks
__global__ __launch_bounds__(1024) void k_scanA(const int* __restrict__ deg,
                                                int* __restrict__ blocksum) {
  int t = threadIdx.x;
  int idx = blockIdx.x * SCAN_CHUNK + t;
  int v = (t < SCAN_CHUNK) ? deg[idx] : 0;
  int lane = t & 63, w = t >> 6;
  int s = wave_red_sum_i(v);
  __shared__ int ws[16];
  if (lane == 0) ws[w] = s;
  __syncthreads();
  if (t == 0) {
    int r = 0;
#pragma unroll
    for (int k = 0; k < 16; k++) r += ws[k];
    blocksum[blockIdx.x] = r;
  }
}

// stage B: per-block exclusive scan + carry from blocksum prefix
__global__ __launch_bounds__(1024) void k_scanB(const int* __restrict__ deg,
                                                const int* __restrict__ blocksum,
                                                int* __restrict__ off) {
  int t = threadIdx.x;
  int b = blockIdx.x;
  int lane = t & 63, w = t >> 6;
  __shared__ int carry_s;
  __shared__ int ws[16];
  if (w == 0) {
    int bs = (lane < b) ? blocksum[lane] : 0;   // b <= 40 <= 64 lanes
    int c = wave_red_sum_i(bs);
    if (lane == 0) carry_s = c;
  }
  int idx = b * SCAN_CHUNK + t;
  int v = (t < SCAN_CHUNK) ? deg[idx] : 0;
  int p = v;
#pragma unroll
  for (int o = 1; o < 64; o <<= 1) {
    int u = __shfl_up(p, o, 64);
    if (lane >= o) p += u;
  }
  if (lane == 63) ws[w] = p;
  __syncthreads();
  if (t == 0) {
    int r = 0;
#pragma unroll
    for (int k = 0; k < 16; k++) { int x = ws[k]; ws[k] = r; r += x; }
  }
  __syncthreads();
  int excl = carry_s + ws[w] + p - v;
  if (t < SCAN_CHUNK) off[idx] = excl;
  if (b == SCAN_BLOCKS - 1 && t == SCAN_CHUNK - 1) off[N_NODES] = excl + v;
}

// atomic-free fill: position = off[d] + erank[i]
__global__ void k_fill(const int* __restrict__ ei, const int* __restrict__ off,
                       const int* __restrict__ erank, int* __restrict__ csr_src) {
  int i = blockIdx.x * blockDim.x + threadIdx.x;
  if (i >= ET) return;
  int s, d;
  if (i < N_EDGES) { s = ei[i]; d = ei[N_EDGES + i]; }
  else             { s = d = i - N_EDGES; }
  csr_src[off[d] + erank[i]] = s;
}

// ---------------- Layer 1: GEMM (x @ W1) + attention dots ----------------
// block = 256 threads (4 waves), M-tile = 32 nodes (grid = 1250 exactly).
__global__ __launch_bounds__(256) void k_gemm1(
    const float* __restrict__ x, const float* __restrict__ W1,
    const float* __restrict__ asv, const float* __restrict__ adv,
    __hip_bfloat16* __restrict__ h1b, float* __restrict__ a_s, float* __restrict__ a_d) {
  __shared__ float xs[32 * 128];           // 16 KB
  int t = threadIdx.x;
  int n0 = blockIdx.x * 32;
  {
    const float4* xg = (const float4*)(x + (size_t)n0 * 128);
    float4* xs4 = (float4*)xs;
#pragma unroll
    for (int i = 0; i < 4; i++) xs4[t + i * 256] = xg[t + i * 256];
  }
  __syncthreads();

  int lane = t & 63;
  int g = t >> 6;
  int c0 = lane * 2;
  const float4* xs4 = (const float4*)(xs + (size_t)g * 8 * 128);

  float2 acc[8];
#pragma unroll
  for (int j = 0; j < 8; j++) acc[j] = make_float2(0.f, 0.f);

  float2 w0 = *(const float2*)(W1 + (size_t)0 * 128 + c0);
  float2 w1 = *(const float2*)(W1 + (size_t)1 * 128 + c0);
  float2 w2 = *(const float2*)(W1 + (size_t)2 * 128 + c0);
  float2 w3 = *(const float2*)(W1 + (size_t)3 * 128 + c0);

  for (int k4 = 0; k4 < 32; k4++) {
    float2 nw0, nw1, nw2, nw3;
    if (k4 < 31) {
      nw0 = *(const float2*)(W1 + (size_t)(4 * k4 + 4) * 128 + c0);
      nw1 = *(const float2*)(W1 + (size_t)(4 * k4 + 5) * 128 + c0);
      nw2 = *(const float2*)(W1 + (size_t)(4 * k4 + 6) * 128 + c0);
      nw3 = *(const float2*)(W1 + (size_t)(4 * k4 + 7) * 128 + c0);
    }
#pragma unroll
    for (int j = 0; j < 8; j++) {
      float4 xv = xs4[j * 32 + k4];           // wave-uniform -> LDS broadcast
      acc[j].x = fmaf(xv.x, w0.x, acc[j].x);
      acc[j].y = fmaf(xv.x, w0.y, acc[j].y);
      acc[j].x = fmaf(xv.y, w1.x, acc[j].x);
      acc[j].y = fmaf(xv.y, w1.y, acc[j].y);
      acc[j].x = fmaf(xv.z, w2.x, acc[j].x);
      acc[j].y = fmaf(xv.z, w2.y, acc[j].y);
      acc[j].x = fmaf(xv.w, w3.x, acc[j].x);
      acc[j].y = fmaf(xv.w, w3.y, acc[j].y);
    }
    w0 = nw0; w1 = nw1; w2 = nw2; w3 = nw3;
  }

  float2 av_s = *(const float2*)(asv + c0);
  float2 av_d = *(const float2*)(adv + c0);
  int head = lane >> 5;
#pragma unroll
  for (int j = 0; j < 8; j++) {
    int n = n0 + g * 8 + j;
    __hip_bfloat162 hv;
    hv.x = __float2bfloat16(acc[j].x);
    hv.y = __float2bfloat16(acc[j].y);
    *(__hip_bfloat162*)(h1b + (size_t)n * 128 + c0) = hv;
    float rs = half_red_sum(acc[j].x * av_s.x + acc[j].y * av_s.y);
    float rd = half_red_sum(acc[j].x * av_d.x + acc[j].y * av_d.y);
    if ((lane & 31) == 0) {
      a_s[n * 2 + head] = rs;
      a_d[n * 2 + head] = rd;
    }
  }
}

// ---------------- per-edge exp in CSR order + denominators ----------------
// one wave per node, lane = edge. exw written coalesced; sums via wave reduction.
__global__ __launch_bounds__(256) void k_exp(
    const int* __restrict__ off, const int* __restrict__ csr_src,
    const float* __restrict__ a_s, const float* __restrict__ a_d,
    float2* __restrict__ exw, float* __restrict__ sums) {
  int v = blockIdx.x * 4 + (threadIdx.x >> 6);
  int lane = threadIdx.x & 63;
  int beg = off[v], end = off[v + 1];
  float2 Ad = *(const float2*)(a_d + 2 * v);
  float s0 = 0.f, s1 = 0.f;
  for (int i = beg + lane; i < end; i += 64) {
    int s = csr_src[i];
    float2 As = *(const float2*)(a_s + 2 * s);
    float e0 = As.x + Ad.x; e0 = (e0 >= 0.f) ? e0 : 0.2f * e0;
    float e1 = As.y + Ad.y; e1 = (e1 >= 0.f) ? e1 : 0.2f * e1;
    float x0 = __expf(e0), x1 = __expf(e1);
    exw[i] = make_float2(x0, x1);
    s0 += x0; s1 += x1;
  }
  s0 = wave_red_sum(s0);
  s1 = wave_red_sum(s1);
  if (lane == 0) { sums[2 * v] = s0; sums[2 * v + 1] = s1; }
}

// ---------------- Layer 1 agg: one wave per node, no shuffles ----------------
// lane l owns features 2l,2l+1; head = l>>5. Edge metadata (csr_src, exw) read
// at wave-uniform sequential addresses (SGPR base) -> scalar/broadcast loads.
// Fused ELU + layer-2 GEMM epilogue; writes packed 32B record {h2[4], a_s2}.
__global__ __launch_bounds__(256) void k_agg1(
    const int* __restrict__ off, const int* __restrict__ csr_src,
    const float2* __restrict__ exw, const float* __restrict__ sums,
    const __hip_bfloat16* __restrict__ h1b, const float* __restrict__ b1,
    const float* __restrict__ W2, const float* __restrict__ as2,
    const float* __restrict__ ad2,
    float* __restrict__ h2pack, float* __restrict__ a_d2) {
  int v = blockIdx.x * 4 + (threadIdx.x >> 6);
  int lane = threadIdx.x & 63;
  int head = lane >> 5;
  int beg = __builtin_amdgcn_readfirstlane(off[v]);
  int end = __builtin_amdgcn_readfirstlane(off[v + 1]);
  float2 sv = *(const float2*)(sums + 2 * v);
  float inv = 1.f / ((head ? sv.y : sv.x) + 1e-16f);
  const __hip_bfloat162* h1b2 = (const __hip_bfloat162*)h1b;

  float acc0 = 0.f, acc1 = 0.f;
  int i = beg;
  for (; i + 4 <= end; i += 4) {
    int sA = csr_src[i + 0];           // uniform sequential -> s_load batch
    int sB = csr_src[i + 1];
    int sC = csr_src[i + 2];
    int sD = csr_src[i + 3];
    float2 wA = exw[i + 0];
    float2 wB = exw[i + 1];
    float2 wC = exw[i + 2];
    float2 wD = exw[i + 3];
    __hip_bfloat162 hA = h1b2[(size_t)sA * 64 + lane];   // 4 gathers in flight
    __hip_bfloat162 hB = h1b2[(size_t)sB * 64 + lane];
    __hip_bfloat162 hC = h1b2[(size_t)sC * 64 + lane];
    __hip_bfloat162 hD = h1b2[(size_t)sD * 64 + lane];
    float eA = head ? wA.y : wA.x;
    float eB = head ? wB.y : wB.x;
    float eC = head ? wC.y : wC.x;
    float eD = head ? wD.y : wD.x;
    acc0 = fmaf(eA, __bfloat162float(hA.x), acc0);
    acc1 = fmaf(eA, __bfloat162float(hA.y), acc1);
    acc0 = fmaf(eB, __bfloat162float(hB.x), acc0);
    acc1 = fmaf(eB, __bfloat162float(hB.y), acc1);
    acc0 = fmaf(eC, __bfloat162float(hC.x), acc0);
    acc1 = fmaf(eC, __bfloat162float(hC.y), acc1);
    acc0 = fmaf(eD, __bfloat162float(hD.x), acc0);
    acc1 = fmaf(eD, __bfloat162float(hD.y), acc1);
  }
  for (; i < end; i++) {
    int s = csr_src[i];
    float2 wv = exw[i];
    float ex = head ? wv.y : wv.x;
    __hip_bfloat162 hv = h1b2[(size_t)s * 64 + lane];
    acc0 = fmaf(ex, __bfloat162float(hv.x), acc0);
    acc1 = fmaf(ex, __bfloat162float(hv.y), acc1);
  }

  float2 bv = *(const float2*)(b1 + 2 * lane);
  float o0 = acc0 * inv + bv.x;
  float o1 = acc1 * inv + bv.y;
  o0 = (o0 > 0.f) ? o0 : expm1f(o0);   // ELU
  o1 = (o1 > 0.f) ? o1 : expm1f(o1);

  // fused layer-2 GEMM: h2[v][j] = sum_f o[f] * W2[f][j]
  float4 wA = *(const float4*)(W2 + (2 * lane) * 4);
  float4 wB = *(const float4*)(W2 + (2 * lane + 1) * 4);
  float p0 = wave_red_sum(o0 * wA.x + o1 * wB.x);
  float p1 = wave_red_sum(o0 * wA.y + o1 * wB.y);
  float p2 = wave_red_sum(o0 * wA.z + o1 * wB.z);
  float p3 = wave_red_sum(o0 * wA.w + o1 * wB.w);
  if (lane == 0) {
    float4 q = {p0, p1, p2, p3};
    *(float4*)(h2pack + (size_t)v * 8) = q;                 // record: h2
    h2pack[(size_t)v * 8 + 4] =
        p0 * as2[0] + p1 * as2[1] + p2 * as2[2] + p3 * as2[3];  // record: a_s2
    a_d2[v] = p0 * ad2[0] + p1 * ad2[1] + p2 * ad2[2] + p3 * ad2[3];
  }
}

// ---------------- Layer 2: fused segment softmax + aggregation + row softmax ----------------
// one 32B-aligned record per src node -> 1 cache line per edge-lane
__global__ __launch_bounds__(256) void k_agg2(
    const int* __restrict__ off, const int* __restrict__ csr_src,
    const float* __restrict__ h2pack, const float* __restrict__ a_d,
    const float* __restrict__ b2, float* __restrict__ out) {
  int v = blockIdx.x * 4 + (threadIdx.x >> 6);
  int lane = threadIdx.x & 63;
  int beg = off[v], end = off[v + 1];
  float adv = a_d[v];
  const float4* pk = (const float4*)h2pack;

  float sum = 0.f;
  float4 acc = {0.f, 0.f, 0.f, 0.f};
  for (int i = beg + lane; i < end; i += 64) {
    int s = csr_src[i];
    float4 r0 = pk[2 * s];          // h2[s]
    float4 r1 = pk[2 * s + 1];      // .x = a_s2[s], same 32B record
    float e = r1.x + adv;
    e = (e >= 0.f) ? e : 0.2f * e;
    float ex = __expf(e);
    sum += ex;
    acc.x = fmaf(ex, r0.x, acc.x);
    acc.y = fmaf(ex, r0.y, acc.y);
    acc.z = fmaf(ex, r0.z, acc.z);
    acc.w = fmaf(ex, r0.w, acc.w);
  }
  sum = wave_red_sum(sum);
  acc.x = wave_red_sum(acc.x);
  acc.y = wave_red_sum(acc.y);
  acc.z = wave_red_sum(acc.z);
  acc.w = wave_red_sum(acc.w);

  if (lane == 0) {
    float invd = 1.f / (sum + 1e-16f);
    float o0 = acc.x * invd + b2[0];
    float o1 = acc.y * invd + b2[1];
    float o2 = acc.z * invd + b2[2];
    float o3 = acc.w * invd + b2[3];
    float mx = fmaxf(fmaxf(o0, o1), fmaxf(o2, o3));
    float e0 = __expf(o0 - mx), e1 = __expf(o1 - mx);
    float e2 = __expf(o2 - mx), e3 = __expf(o3 - mx);
    float s4 = e0 + e1 + e2 + e3;
    float4 r = {e0 / s4, e1 / s4, e2 / s4, e3 / s4};
    *(float4*)(out + (size_t)v * 4) = r;
  }
}

extern "C" void kernel_launch(void* const* d_in, const int* in_sizes, int n_in,
                              void* d_out, int out_size, void* d_ws, size_t ws_size,
                              hipStream_t stream) {
  const float* x   = (const float*)d_in[0];
  const int*   ei  = (const int*)d_in[1];   // [2, E]: row0 = src, row1 = dst
  const float* W1  = (const float*)d_in[3];
  const float* as1 = (const float*)d_in[4];
  const float* ad1 = (const float*)d_in[5];
  const float* b1  = (const float*)d_in[6];
  const float* W2  = (const float*)d_in[7];
  const float* as2 = (const float*)d_in[8];
  const float* ad2 = (const float*)d_in[9];
  const float* b2  = (const float*)d_in[10];
  float* out = (float*)d_out;

  char* w = (char*)d_ws;
  auto alloc = [&](size_t bytes) {
    char* p = w;
    w += (bytes + 255) & ~(size_t)255;
    return p;
  };
  int*   deg     = (int*)alloc((size_t)N_NODES * 4);
  int*   off     = (int*)alloc((size_t)(N_NODES + 1) * 4);
  int*   erank   = (int*)alloc((size_t)ET * 4);
  int*   csr_src = (int*)alloc((size_t)ET * 4);
  int*   blocksum= (int*)alloc((size_t)SCAN_BLOCKS * 4);
  __hip_bfloat16* h1b = (__hip_bfloat16*)alloc((size_t)N_NODES * 128 * 2);
  float* a_s1w   = (float*)alloc((size_t)N_NODES * 2 * 4);
  float* a_d1w   = (float*)alloc((size_t)N_NODES * 2 * 4);
  float2* exw    = (float2*)alloc((size_t)ET * 8);
  float* sums    = (float*)alloc((size_t)N_NODES * 2 * 4);
  float* h2pack  = (float*)alloc((size_t)N_NODES * 8 * 4);   // 32B records
  float* a_d2w   = (float*)alloc((size_t)N_NODES * 4);

  hipMemsetAsync(deg, 0, (size_t)N_NODES * 4, stream);
  k_hist<<<(ET + 255) / 256, 256, 0, stream>>>(ei, deg, erank);
  k_scanA<<<SCAN_BLOCKS, 1024, 0, stream>>>(deg, blocksum);
  k_scanB<<<SCAN_BLOCKS, 1024, 0, stream>>>(deg, blocksum, off);
  k_fill<<<(ET + 255) / 256, 256, 0, stream>>>(ei, off, erank, csr_src);

  k_gemm1<<<N_NODES / 32, 256, 0, stream>>>(x, W1, as1, ad1, h1b, a_s1w, a_d1w);
  k_exp<<<N_NODES / 4, 256, 0, stream>>>(off, csr_src, a_s1w, a_d1w, exw, sums);
  k_agg1<<<N_NODES / 4, 256, 0, stream>>>(off, csr_src, exw, sums, h1b, b1,
                                          W2, as2, ad2, h2pack, a_d2w);
  k_agg2<<<N_NODES / 4, 256, 0, stream>>>(off, csr_src, h2pack, a_d2w, b2, out);
}

// Round 10
// 201.176 us; speedup vs baseline: 1.0553x; 1.0553x over previous
//
#include <hip/hip_runtime.h>
#include <hip/hip_bf16.h>
#include <math.h>

#define N_NODES 40000
#define N_EDGES 640000
#define ET (N_EDGES + N_NODES)   // 680000 total edges incl. self-loops
#define SCAN_BLOCKS 40
#define SCAN_CHUNK 1000          // 40 * 1000 = 40000
#define G1_BLOCKS 1250           // 40000/32
#define EPB 544                  // edges per gemm1 block: 1250*544 = 680000

__device__ __forceinline__ float wave_red_sum(float v) {
#pragma unroll
  for (int m = 32; m >= 1; m >>= 1) v += __shfl_xor(v, m, 64);
  return v;
}
__device__ __forceinline__ int wave_red_sum_i(int v) {
#pragma unroll
  for (int m = 32; m >= 1; m >>= 1) v += __shfl_xor(v, m, 64);
  return v;
}
__device__ __forceinline__ float half_red_sum(float v) {
#pragma unroll
  for (int m = 16; m >= 1; m >>= 1) v += __shfl_xor(v, m, 64);
  return v;
}

// hierarchical scan, stage A: per-block sums of 1000-element chunks
__global__ __launch_bounds__(1024) void k_scanA(const int* __restrict__ deg,
                                                int* __restrict__ blocksum) {
  int t = threadIdx.x;
  int idx = blockIdx.x * SCAN_CHUNK + t;
  int v = (t < SCAN_CHUNK) ? deg[idx] : 0;
  int lane = t & 63, w = t >> 6;
  int s = wave_red_sum_i(v);
  __shared__ int ws[16];
  if (lane == 0) ws[w] = s;
  __syncthreads();
  if (t == 0) {
    int r = 0;
#pragma unroll
    for (int k = 0; k < 16; k++) r += ws[k];
    blocksum[blockIdx.x] = r;
  }
}

// stage B: per-block exclusive scan + carry from blocksum prefix
__global__ __launch_bounds__(1024) void k_scanB(const int* __restrict__ deg,
                                                const int* __restrict__ blocksum,
                                                int* __restrict__ off) {
  int t = threadIdx.x;
  int b = blockIdx.x;
  int lane = t & 63, w = t >> 6;
  __shared__ int carry_s;
  __shared__ int ws[16];
  if (w == 0) {
    int bs = (lane < b) ? blocksum[lane] : 0;   // b <= 40 <= 64 lanes
    int c = wave_red_sum_i(bs);
    if (lane == 0) carry_s = c;
  }
  int idx = b * SCAN_CHUNK + t;
  int v = (t < SCAN_CHUNK) ? deg[idx] : 0;
  int p = v;
#pragma unroll
  for (int o = 1; o < 64; o <<= 1) {
    int u = __shfl_up(p, o, 64);
    if (lane >= o) p += u;
  }
  if (lane == 63) ws[w] = p;
  __syncthreads();
  if (t == 0) {
    int r = 0;
#pragma unroll
    for (int k = 0; k < 16; k++) { int x = ws[k]; ws[k] = r; r += x; }
  }
  __syncthreads();
  int excl = carry_s + ws[w] + p - v;
  if (t < SCAN_CHUNK) off[idx] = excl;
  if (b == SCAN_BLOCKS - 1 && t == SCAN_CHUNK - 1) off[N_NODES] = excl + v;
}

// atomic-free fill: position = off[d] + erank[i]
__global__ void k_fill(const int* __restrict__ ei, const int* __restrict__ off,
                       const int* __restrict__ erank, int* __restrict__ csr_src) {
  int i = blockIdx.x * blockDim.x + threadIdx.x;
  if (i >= ET) return;
  int s, d;
  if (i < N_EDGES) { s = ei[i]; d = ei[N_EDGES + i]; }
  else             { s = d = i - N_EDGES; }
  csr_src[off[d] + erank[i]] = s;
}

// ---------------- Layer 1 GEMM (x @ W1) + attention dots + FUSED edge histogram ----------------
// block = 256 threads (4 waves), M-tile = 32 nodes (grid = 1250 exactly).
// Each block also histograms its 544-edge slice; atomic latency hides under GEMM.
__global__ __launch_bounds__(256) void k_gemm1(
    const float* __restrict__ x, const float* __restrict__ W1,
    const float* __restrict__ asv, const float* __restrict__ adv,
    const int* __restrict__ ei, int* __restrict__ deg, int* __restrict__ erank,
    __hip_bfloat16* __restrict__ h1b, float* __restrict__ a_s, float* __restrict__ a_d) {
  __shared__ float xs[32 * 128];           // 16 KB
  int t = threadIdx.x;
  int n0 = blockIdx.x * 32;

  // issue x-tile loads
  const float4* xg = (const float4*)(x + (size_t)n0 * 128);
  float4 xr0 = xg[t + 0 * 256];
  float4 xr1 = xg[t + 1 * 256];
  float4 xr2 = xg[t + 2 * 256];
  float4 xr3 = xg[t + 3 * 256];

  // fused histogram slice (independent work; hides atomic latency)
  {
    int ebase = blockIdx.x * EPB;
#pragma unroll
    for (int r = 0; r < 2; r++) {
      int i = ebase + r * 256 + t;
      int d = (i < N_EDGES) ? ei[N_EDGES + i] : (i - N_EDGES);
      erank[i] = atomicAdd(&deg[d], 1);
    }
    if (t < EPB - 512) {
      int i = ebase + 512 + t;
      int d = (i < N_EDGES) ? ei[N_EDGES + i] : (i - N_EDGES);
      erank[i] = atomicAdd(&deg[d], 1);
    }
  }

  float4* xs4w = (float4*)xs;
  xs4w[t + 0 * 256] = xr0;
  xs4w[t + 1 * 256] = xr1;
  xs4w[t + 2 * 256] = xr2;
  xs4w[t + 3 * 256] = xr3;
  __syncthreads();

  int lane = t & 63;
  int g = t >> 6;
  int c0 = lane * 2;
  const float4* xs4 = (const float4*)(xs + (size_t)g * 8 * 128);

  float2 acc[8];
#pragma unroll
  for (int j = 0; j < 8; j++) acc[j] = make_float2(0.f, 0.f);

  float2 w0 = *(const float2*)(W1 + (size_t)0 * 128 + c0);
  float2 w1 = *(const float2*)(W1 + (size_t)1 * 128 + c0);
  float2 w2 = *(const float2*)(W1 + (size_t)2 * 128 + c0);
  float2 w3 = *(const float2*)(W1 + (size_t)3 * 128 + c0);

  for (int k4 = 0; k4 < 32; k4++) {
    float2 nw0, nw1, nw2, nw3;
    if (k4 < 31) {
      nw0 = *(const float2*)(W1 + (size_t)(4 * k4 + 4) * 128 + c0);
      nw1 = *(const float2*)(W1 + (size_t)(4 * k4 + 5) * 128 + c0);
      nw2 = *(const float2*)(W1 + (size_t)(4 * k4 + 6) * 128 + c0);
      nw3 = *(const float2*)(W1 + (size_t)(4 * k4 + 7) * 128 + c0);
    }
#pragma unroll
    for (int j = 0; j < 8; j++) {
      float4 xv = xs4[j * 32 + k4];           // wave-uniform -> LDS broadcast
      acc[j].x = fmaf(xv.x, w0.x, acc[j].x);
      acc[j].y = fmaf(xv.x, w0.y, acc[j].y);
      acc[j].x = fmaf(xv.y, w1.x, acc[j].x);
      acc[j].y = fmaf(xv.y, w1.y, acc[j].y);
      acc[j].x = fmaf(xv.z, w2.x, acc[j].x);
      acc[j].y = fmaf(xv.z, w2.y, acc[j].y);
      acc[j].x = fmaf(xv.w, w3.x, acc[j].x);
      acc[j].y = fmaf(xv.w, w3.y, acc[j].y);
    }
    w0 = nw0; w1 = nw1; w2 = nw2; w3 = nw3;
  }

  float2 av_s = *(const float2*)(asv + c0);
  float2 av_d = *(const float2*)(adv + c0);
  int head = lane >> 5;
#pragma unroll
  for (int j = 0; j < 8; j++) {
    int n = n0 + g * 8 + j;
    __hip_bfloat162 hv;
    hv.x = __float2bfloat16(acc[j].x);
    hv.y = __float2bfloat16(acc[j].y);
    *(__hip_bfloat162*)(h1b + (size_t)n * 128 + c0) = hv;
    float rs = half_red_sum(acc[j].x * av_s.x + acc[j].y * av_s.y);
    float rd = half_red_sum(acc[j].x * av_d.x + acc[j].y * av_d.y);
    if ((lane & 31) == 0) {
      a_s[n * 2 + head] = rs;
      a_d[n * 2 + head] = rd;
    }
  }
}

// ---------------- Layer 1 agg: one wave per node, LDS-staged edge data ----------------
// Per 64-edge chunk: lanes compute (src, ex0, ex1) in parallel -> wave-private LDS
// slice -> fence -> j-loop broadcast-reads LDS, 4 h1 gathers in flight.
// No __syncthreads (divergent trip counts); no shuffles in hot loop; no k_exp pass.
// Fused ELU + layer-2 GEMM epilogue; writes packed 32B record {h2[4], a_s2}.
__global__ __launch_bounds__(256) void k_agg1(
    const int* __restrict__ off, const int* __restrict__ csr_src,
    const float* __restrict__ a_s, const float* __restrict__ a_d,
    const __hip_bfloat16* __restrict__ h1b, const float* __restrict__ b1,
    const float* __restrict__ W2, const float* __restrict__ as2,
    const float* __restrict__ ad2,
    float* __restrict__ h2pack, float* __restrict__ a_d2) {
  int wv = threadIdx.x >> 6;
  int v = blockIdx.x * 4 + wv;
  int lane = threadIdx.x & 63;
  int head = lane >> 5;
  int beg = off[v], end = off[v + 1];
  float2 Ad = *(const float2*)(a_d + 2 * v);
  const __hip_bfloat162* h1b2 = (const __hip_bfloat162*)h1b;

  __shared__ int    lds_s[4][64];
  __shared__ float2 lds_e[4][64];

  float acc0 = 0.f, acc1 = 0.f;
  float sum0 = 0.f, sum1 = 0.f;
  for (int base = beg; base < end; base += 64) {
    int idx = base + lane;
    int sreg = 0;
    float ex0 = 0.f, ex1 = 0.f;
    if (idx < end) {
      sreg = csr_src[idx];
      float2 As = *(const float2*)(a_s + 2 * sreg);
      float e0 = As.x + Ad.x; e0 = (e0 >= 0.f) ? e0 : 0.2f * e0;
      float e1 = As.y + Ad.y; e1 = (e1 >= 0.f) ? e1 : 0.2f * e1;
      ex0 = __expf(e0); ex1 = __expf(e1);
    }
    sum0 += ex0; sum1 += ex1;
    lds_s[wv][lane] = sreg;
    lds_e[wv][lane] = make_float2(ex0, ex1);
    __threadfence_block();               // wave-local LDS visibility (no barrier!)

    int jmax = min(64, end - base);
    int j = 0;
    for (; j + 4 <= jmax; j += 4) {
      int sA = lds_s[wv][j + 0];         // uniform addr -> LDS broadcast
      int sB = lds_s[wv][j + 1];
      int sC = lds_s[wv][j + 2];
      int sD = lds_s[wv][j + 3];
      float2 wA = lds_e[wv][j + 0];
      float2 wB = lds_e[wv][j + 1];
      float2 wC = lds_e[wv][j + 2];
      float2 wD = lds_e[wv][j + 3];
      __hip_bfloat162 hA = h1b2[(size_t)sA * 64 + lane];   // 4 gathers in flight
      __hip_bfloat162 hB = h1b2[(size_t)sB * 64 + lane];
      __hip_bfloat162 hC = h1b2[(size_t)sC * 64 + lane];
      __hip_bfloat162 hD = h1b2[(size_t)sD * 64 + lane];
      float eA = head ? wA.y : wA.x;
      float eB = head ? wB.y : wB.x;
      float eC = head ? wC.y : wC.x;
      float eD = head ? wD.y : wD.x;
      acc0 = fmaf(eA, __bfloat162float(hA.x), acc0);
      acc1 = fmaf(eA, __bfloat162float(hA.y), acc1);
      acc0 = fmaf(eB, __bfloat162float(hB.x), acc0);
      acc1 = fmaf(eB, __bfloat162float(hB.y), acc1);
      acc0 = fmaf(eC, __bfloat162float(hC.x), acc0);
      acc1 = fmaf(eC, __bfloat162float(hC.y), acc1);
      acc0 = fmaf(eD, __bfloat162float(hD.x), acc0);
      acc1 = fmaf(eD, __bfloat162float(hD.y), acc1);
    }
    for (; j < jmax; j++) {
      int s = lds_s[wv][j];
      float2 wv2 = lds_e[wv][j];
      float ex = head ? wv2.y : wv2.x;
      __hip_bfloat162 hv = h1b2[(size_t)s * 64 + lane];
      acc0 = fmaf(ex, __bfloat162float(hv.x), acc0);
      acc1 = fmaf(ex, __bfloat162float(hv.y), acc1);
    }
    __threadfence_block();               // drain reads before next chunk's writes
  }
  sum0 = wave_red_sum(sum0);
  sum1 = wave_red_sum(sum1);
  float inv = 1.f / ((head ? sum1 : sum0) + 1e-16f);

  float2 bv = *(const float2*)(b1 + 2 * lane);
  float o0 = acc0 * inv + bv.x;
  float o1 = acc1 * inv + bv.y;
  o0 = (o0 > 0.f) ? o0 : expm1f(o0);   // ELU
  o1 = (o1 > 0.f) ? o1 : expm1f(o1);

  // fused layer-2 GEMM: h2[v][j] = sum_f o[f] * W2[f][j]
  float4 wA = *(const float4*)(W2 + (2 * lane) * 4);
  float4 wB = *(const float4*)(W2 + (2 * lane + 1) * 4);
  float p0 = wave_red_sum(o0 * wA.x + o1 * wB.x);
  float p1 = wave_red_sum(o0 * wA.y + o1 * wB.y);
  float p2 = wave_red_sum(o0 * wA.z + o1 * wB.z);
  float p3 = wave_red_sum(o0 * wA.w + o1 * wB.w);
  if (lane == 0) {
    float4 q = {p0, p1, p2, p3};
    *(float4*)(h2pack + (size_t)v * 8) = q;                 // record: h2
    h2pack[(size_t)v * 8 + 4] =
        p0 * as2[0] + p1 * as2[1] + p2 * as2[2] + p3 * as2[3];  // record: a_s2
    a_d2[v] = p0 * ad2[0] + p1 * ad2[1] + p2 * ad2[2] + p3 * ad2[3];
  }
}

// ---------------- Layer 2: fused segment softmax + aggregation + row softmax ----------------
// one 32B-aligned record per src node -> 1 cache line per edge-lane
__global__ __launch_bounds__(256) void k_agg2(
    const int* __restrict__ off, const int* __restrict__ csr_src,
    const float* __restrict__ h2pack, const float* __restrict__ a_d,
    const float* __restrict__ b2, float* __restrict__ out) {
  int v = blockIdx.x * 4 + (threadIdx.x >> 6);
  int lane = threadIdx.x & 63;
  int beg = off[v], end = off[v + 1];
  float adv = a_d[v];
  const float4* pk = (const float4*)h2pack;

  float sum = 0.f;
  float4 acc = {0.f, 0.f, 0.f, 0.f};
  for (int i = beg + lane; i < end; i += 64) {
    int s = csr_src[i];
    float4 r0 = pk[2 * s];          // h2[s]
    float4 r1 = pk[2 * s + 1];      // .x = a_s2[s], same 32B record
    float e = r1.x + adv;
    e = (e >= 0.f) ? e : 0.2f * e;
    float ex = __expf(e);
    sum += ex;
    acc.x = fmaf(ex, r0.x, acc.x);
    acc.y = fmaf(ex, r0.y, acc.y);
    acc.z = fmaf(ex, r0.z, acc.z);
    acc.w = fmaf(ex, r0.w, acc.w);
  }
  sum = wave_red_sum(sum);
  acc.x = wave_red_sum(acc.x);
  acc.y = wave_red_sum(acc.y);
  acc.z = wave_red_sum(acc.z);
  acc.w = wave_red_sum(acc.w);

  if (lane == 0) {
    float invd = 1.f / (sum + 1e-16f);
    float o0 = acc.x * invd + b2[0];
    float o1 = acc.y * invd + b2[1];
    float o2 = acc.z * invd + b2[2];
    float o3 = acc.w * invd + b2[3];
    float mx = fmaxf(fmaxf(o0, o1), fmaxf(o2, o3));
    float e0 = __expf(o0 - mx), e1 = __expf(o1 - mx);
    float e2 = __expf(o2 - mx), e3 = __expf(o3 - mx);
    float s4 = e0 + e1 + e2 + e3;
    float4 r = {e0 / s4, e1 / s4, e2 / s4, e3 / s4};
    *(float4*)(out + (size_t)v * 4) = r;
  }
}

extern "C" void kernel_launch(void* const* d_in, const int* in_sizes, int n_in,
                              void* d_out, int out_size, void* d_ws, size_t ws_size,
                              hipStream_t stream) {
  const float* x   = (const float*)d_in[0];
  const int*   ei  = (const int*)d_in[1];   // [2, E]: row0 = src, row1 = dst
  const float* W1  = (const float*)d_in[3];
  const float* as1 = (const float*)d_in[4];
  const float* ad1 = (const float*)d_in[5];
  const float* b1  = (const float*)d_in[6];
  const float* W2  = (const float*)d_in[7];
  const float* as2 = (const float*)d_in[8];
  const float* ad2 = (const float*)d_in[9];
  const float* b2  = (const float*)d_in[10];
  float* out = (float*)d_out;

  char* w = (char*)d_ws;
  auto alloc = [&](size_t bytes) {
    char* p = w;
    w += (bytes + 255) & ~(size_t)255;
    return p;
  };
  int*   deg     = (int*)alloc((size_t)N_NODES * 4);
  int*   off     = (int*)alloc((size_t)(N_NODES + 1) * 4);
  int*   erank   = (int*)alloc((size_t)ET * 4);
  int*   csr_src = (int*)alloc((size_t)ET * 4);
  int*   blocksum= (int*)alloc((size_t)SCAN_BLOCKS * 4);
  __hip_bfloat16* h1b = (__hip_bfloat16*)alloc((size_t)N_NODES * 128 * 2);
  float* a_s1w   = (float*)alloc((size_t)N_NODES * 2 * 4);
  float* a_d1w   = (float*)alloc((size_t)N_NODES * 2 * 4);
  float* h2pack  = (float*)alloc((size_t)N_NODES * 8 * 4);   // 32B records
  float* a_d2w   = (float*)alloc((size_t)N_NODES * 4);

  hipMemsetAsync(deg, 0, (size_t)N_NODES * 4, stream);
  // gemm1 carries the edge histogram (independent work, hides atomic latency)
  k_gemm1<<<G1_BLOCKS, 256, 0, stream>>>(x, W1, as1, ad1, ei, deg, erank,
                                         h1b, a_s1w, a_d1w);
  k_scanA<<<SCAN_BLOCKS, 1024, 0, stream>>>(deg, blocksum);
  k_scanB<<<SCAN_BLOCKS, 1024, 0, stream>>>(deg, blocksum, off);
  k_fill<<<(ET + 255) / 256, 256, 0, stream>>>(ei, off, erank, csr_src);

  k_agg1<<<N_NODES / 4, 256, 0, stream>>>(off, csr_src, a_s1w, a_d1w, h1b, b1,
                                          W2, as2, ad2, h2pack, a_d2w);
  k_agg2<<<N_NODES / 4, 256, 0, stream>>>(off, csr_src, h2pack, a_d2w, b2, out);
}

// Round 11
// 195.710 us; speedup vs baseline: 1.0848x; 1.0279x over previous
//
#include <hip/hip_runtime.h>
#include <hip/hip_bf16.h>
#include <math.h>

#define N_NODES 40000
#define N_EDGES 640000
#define ET (N_EDGES + N_NODES)   // 680000 total edges incl. self-loops
#define SCAN_BLOCKS 40
#define SCAN_CHUNK 1000          // 40 * 1000 = 40000

__device__ __forceinline__ float wave_red_sum(float v) {
#pragma unroll
  for (int m = 32; m >= 1; m >>= 1) v += __shfl_xor(v, m, 64);
  return v;
}
__device__ __forceinline__ int wave_red_sum_i(int v) {
#pragma unroll
  for (int m = 32; m >= 1; m >>= 1) v += __shfl_xor(v, m, 64);
  return v;
}
__device__ __forceinline__ float half_red_sum(float v) {
#pragma unroll
  for (int m = 16; m >= 1; m >>= 1) v += __shfl_xor(v, m, 64);
  return v;
}
// reduction within 16-lane groups (xor masks < 16 stay in-group)
__device__ __forceinline__ float red16(float v) {
#pragma unroll
  for (int m = 8; m >= 1; m >>= 1) v += __shfl_xor(v, m, 64);
  return v;
}

// ---------------- CSR build ----------------
// hist also records each edge's arrival rank within its dst bucket -> no atomic in k_fill
__global__ void k_hist(const int* __restrict__ ei, int* __restrict__ deg,
                       int* __restrict__ erank) {
  int i = blockIdx.x * blockDim.x + threadIdx.x;
  if (i >= ET) return;
  int d = (i < N_EDGES) ? ei[N_EDGES + i] : (i - N_EDGES);
  erank[i] = atomicAdd(&deg[d], 1);
}

// hierarchical scan, stage A: per-block sums of 1000-element chunks
__global__ __launch_bounds__(1024) void k_scanA(const int* __restrict__ deg,
                                                int* __restrict__ blocksum) {
  int t = threadIdx.x;
  int idx = blockIdx.x * SCAN_CHUNK + t;
  int v = (t < SCAN_CHUNK) ? deg[idx] : 0;
  int lane = t & 63, w = t >> 6;
  int s = wave_red_sum_i(v);
  __shared__ int ws[16];
  if (lane == 0) ws[w] = s;
  __syncthreads();
  if (t == 0) {
    int r = 0;
#pragma unroll
    for (int k = 0; k < 16; k++) r += ws[k];
    blocksum[blockIdx.x] = r;
  }
}

// stage B: per-block exclusive scan + carry from blocksum prefix
__global__ __launch_bounds__(1024) void k_scanB(const int* __restrict__ deg,
                                                const int* __restrict__ blocksum,
                                                int* __restrict__ off) {
  int t = threadIdx.x;
  int b = blockIdx.x;
  int lane = t & 63, w = t >> 6;
  __shared__ int carry_s;
  __shared__ int ws[16];
  if (w == 0) {
    int bs = (lane < b) ? blocksum[lane] : 0;   // b <= 40 <= 64 lanes
    int c = wave_red_sum_i(bs);
    if (lane == 0) carry_s = c;
  }
  int idx = b * SCAN_CHUNK + t;
  int v = (t < SCAN_CHUNK) ? deg[idx] : 0;
  int p = v;
#pragma unroll
  for (int o = 1; o < 64; o <<= 1) {
    int u = __shfl_up(p, o, 64);
    if (lane >= o) p += u;
  }
  if (lane == 63) ws[w] = p;
  __syncthreads();
  if (t == 0) {
    int r = 0;
#pragma unroll
    for (int k = 0; k < 16; k++) { int x = ws[k]; ws[k] = r; r += x; }
  }
  __syncthreads();
  int excl = carry_s + ws[w] + p - v;
  if (t < SCAN_CHUNK) off[idx] = excl;
  if (b == SCAN_BLOCKS - 1 && t == SCAN_CHUNK - 1) off[N_NODES] = excl + v;
}

// atomic-free fill: position = off[d] + erank[i]
__global__ void k_fill(const int* __restrict__ ei, const int* __restrict__ off,
                       const int* __restrict__ erank, int* __restrict__ csr_src) {
  int i = blockIdx.x * blockDim.x + threadIdx.x;
  if (i >= ET) return;
  int s, d;
  if (i < N_EDGES) { s = ei[i]; d = ei[N_EDGES + i]; }
  else             { s = d = i - N_EDGES; }
  csr_src[off[d] + erank[i]] = s;
}

// ---------------- Layer 1: GEMM (x @ W1) + attention dots ----------------
// block = 256 threads (4 waves), M-tile = 32 nodes (grid = 1250 exactly).
__global__ __launch_bounds__(256) void k_gemm1(
    const float* __restrict__ x, const float* __restrict__ W1,
    const float* __restrict__ asv, const float* __restrict__ adv,
    __hip_bfloat16* __restrict__ h1b, float* __restrict__ a_s, float* __restrict__ a_d) {
  __shared__ float xs[32 * 128];           // 16 KB
  int t = threadIdx.x;
  int n0 = blockIdx.x * 32;
  {
    const float4* xg = (const float4*)(x + (size_t)n0 * 128);
    float4* xs4 = (float4*)xs;
#pragma unroll
    for (int i = 0; i < 4; i++) xs4[t + i * 256] = xg[t + i * 256];
  }
  __syncthreads();

  int lane = t & 63;
  int g = t >> 6;
  int c0 = lane * 2;
  const float4* xs4 = (const float4*)(xs + (size_t)g * 8 * 128);

  float2 acc[8];
#pragma unroll
  for (int j = 0; j < 8; j++) acc[j] = make_float2(0.f, 0.f);

  float2 w0 = *(const float2*)(W1 + (size_t)0 * 128 + c0);
  float2 w1 = *(const float2*)(W1 + (size_t)1 * 128 + c0);
  float2 w2 = *(const float2*)(W1 + (size_t)2 * 128 + c0);
  float2 w3 = *(const float2*)(W1 + (size_t)3 * 128 + c0);

  for (int k4 = 0; k4 < 32; k4++) {
    float2 nw0, nw1, nw2, nw3;
    if (k4 < 31) {
      nw0 = *(const float2*)(W1 + (size_t)(4 * k4 + 4) * 128 + c0);
      nw1 = *(const float2*)(W1 + (size_t)(4 * k4 + 5) * 128 + c0);
      nw2 = *(const float2*)(W1 + (size_t)(4 * k4 + 6) * 128 + c0);
      nw3 = *(const float2*)(W1 + (size_t)(4 * k4 + 7) * 128 + c0);
    }
#pragma unroll
    for (int j = 0; j < 8; j++) {
      float4 xv = xs4[j * 32 + k4];           // wave-uniform -> LDS broadcast
      acc[j].x = fmaf(xv.x, w0.x, acc[j].x);
      acc[j].y = fmaf(xv.x, w0.y, acc[j].y);
      acc[j].x = fmaf(xv.y, w1.x, acc[j].x);
      acc[j].y = fmaf(xv.y, w1.y, acc[j].y);
      acc[j].x = fmaf(xv.z, w2.x, acc[j].x);
      acc[j].y = fmaf(xv.z, w2.y, acc[j].y);
      acc[j].x = fmaf(xv.w, w3.x, acc[j].x);
      acc[j].y = fmaf(xv.w, w3.y, acc[j].y);
    }
    w0 = nw0; w1 = nw1; w2 = nw2; w3 = nw3;
  }

  float2 av_s = *(const float2*)(asv + c0);
  float2 av_d = *(const float2*)(adv + c0);
  int head = lane >> 5;
#pragma unroll
  for (int j = 0; j < 8; j++) {
    int n = n0 + g * 8 + j;
    __hip_bfloat162 hv;
    hv.x = __float2bfloat16(acc[j].x);
    hv.y = __float2bfloat16(acc[j].y);
    *(__hip_bfloat162*)(h1b + (size_t)n * 128 + c0) = hv;
    float rs = half_red_sum(acc[j].x * av_s.x + acc[j].y * av_s.y);
    float rd = half_red_sum(acc[j].x * av_d.x + acc[j].y * av_d.y);
    if ((lane & 31) == 0) {
      a_s[n * 2 + head] = rs;
      a_d[n * 2 + head] = rd;
    }
  }
}

// ---------------- Layer 1 agg: one wave per node, LDS-staged edge data ----------------
// Per 64-edge chunk: lanes compute (src, ex0, ex1) in parallel -> wave-private LDS
// slice -> fence -> j-loop broadcast-reads LDS, 4 h1 gathers in flight.
// Fused ELU + layer-2 GEMM epilogue; writes packed 32B record {h2[4], a_s2}.
__global__ __launch_bounds__(256) void k_agg1(
    const int* __restrict__ off, const int* __restrict__ csr_src,
    const float* __restrict__ a_s, const float* __restrict__ a_d,
    const __hip_bfloat16* __restrict__ h1b, const float* __restrict__ b1,
    const float* __restrict__ W2, const float* __restrict__ as2,
    const float* __restrict__ ad2,
    float* __restrict__ h2pack, float* __restrict__ a_d2) {
  int wv = threadIdx.x >> 6;
  int v = blockIdx.x * 4 + wv;
  int lane = threadIdx.x & 63;
  int head = lane >> 5;
  int beg = off[v], end = off[v + 1];
  float2 Ad = *(const float2*)(a_d + 2 * v);
  const __hip_bfloat162* h1b2 = (const __hip_bfloat162*)h1b;

  __shared__ int    lds_s[4][64];
  __shared__ float2 lds_e[4][64];

  float acc0 = 0.f, acc1 = 0.f;
  float sum0 = 0.f, sum1 = 0.f;
  for (int base = beg; base < end; base += 64) {
    int idx = base + lane;
    int sreg = 0;
    float ex0 = 0.f, ex1 = 0.f;
    if (idx < end) {
      sreg = csr_src[idx];
      float2 As = *(const float2*)(a_s + 2 * sreg);
      float e0 = As.x + Ad.x; e0 = (e0 >= 0.f) ? e0 : 0.2f * e0;
      float e1 = As.y + Ad.y; e1 = (e1 >= 0.f) ? e1 : 0.2f * e1;
      ex0 = __expf(e0); ex1 = __expf(e1);
    }
    sum0 += ex0; sum1 += ex1;
    lds_s[wv][lane] = sreg;
    lds_e[wv][lane] = make_float2(ex0, ex1);
    __threadfence_block();               // wave-local LDS visibility (no barrier!)

    int jmax = min(64, end - base);
    int j = 0;
    for (; j + 4 <= jmax; j += 4) {
      int sA = lds_s[wv][j + 0];         // uniform addr -> LDS broadcast
      int sB = lds_s[wv][j + 1];
      int sC = lds_s[wv][j + 2];
      int sD = lds_s[wv][j + 3];
      float2 wA = lds_e[wv][j + 0];
      float2 wB = lds_e[wv][j + 1];
      float2 wC = lds_e[wv][j + 2];
      float2 wD = lds_e[wv][j + 3];
      __hip_bfloat162 hA = h1b2[(size_t)sA * 64 + lane];   // 4 gathers in flight
      __hip_bfloat162 hB = h1b2[(size_t)sB * 64 + lane];
      __hip_bfloat162 hC = h1b2[(size_t)sC * 64 + lane];
      __hip_bfloat162 hD = h1b2[(size_t)sD * 64 + lane];
      float eA = head ? wA.y : wA.x;
      float eB = head ? wB.y : wB.x;
      float eC = head ? wC.y : wC.x;
      float eD = head ? wD.y : wD.x;
      acc0 = fmaf(eA, __bfloat162float(hA.x), acc0);
      acc1 = fmaf(eA, __bfloat162float(hA.y), acc1);
      acc0 = fmaf(eB, __bfloat162float(hB.x), acc0);
      acc1 = fmaf(eB, __bfloat162float(hB.y), acc1);
      acc0 = fmaf(eC, __bfloat162float(hC.x), acc0);
      acc1 = fmaf(eC, __bfloat162float(hC.y), acc1);
      acc0 = fmaf(eD, __bfloat162float(hD.x), acc0);
      acc1 = fmaf(eD, __bfloat162float(hD.y), acc1);
    }
    for (; j < jmax; j++) {
      int s = lds_s[wv][j];
      float2 wv2 = lds_e[wv][j];
      float ex = head ? wv2.y : wv2.x;
      __hip_bfloat162 hv = h1b2[(size_t)s * 64 + lane];
      acc0 = fmaf(ex, __bfloat162float(hv.x), acc0);
      acc1 = fmaf(ex, __bfloat162float(hv.y), acc1);
    }
    __threadfence_block();               // drain reads before next chunk's writes
  }
  sum0 = wave_red_sum(sum0);
  sum1 = wave_red_sum(sum1);
  float inv = 1.f / ((head ? sum1 : sum0) + 1e-16f);

  float2 bv = *(const float2*)(b1 + 2 * lane);
  float o0 = acc0 * inv + bv.x;
  float o1 = acc1 * inv + bv.y;
  o0 = (o0 > 0.f) ? o0 : expm1f(o0);   // ELU
  o1 = (o1 > 0.f) ? o1 : expm1f(o1);

  // fused layer-2 GEMM: h2[v][j] = sum_f o[f] * W2[f][j]
  float4 wA = *(const float4*)(W2 + (2 * lane) * 4);
  float4 wB = *(const float4*)(W2 + (2 * lane + 1) * 4);
  float p0 = wave_red_sum(o0 * wA.x + o1 * wB.x);
  float p1 = wave_red_sum(o0 * wA.y + o1 * wB.y);
  float p2 = wave_red_sum(o0 * wA.z + o1 * wB.z);
  float p3 = wave_red_sum(o0 * wA.w + o1 * wB.w);
  if (lane == 0) {
    float4 q = {p0, p1, p2, p3};
    *(float4*)(h2pack + (size_t)v * 8) = q;                 // record: h2
    h2pack[(size_t)v * 8 + 4] =
        p0 * as2[0] + p1 * as2[1] + p2 * as2[2] + p3 * as2[3];  // record: a_s2
    a_d2[v] = p0 * ad2[0] + p1 * ad2[1] + p2 * ad2[2] + p3 * ad2[3];
  }
}

// ---------------- Layer 2: fused segment softmax + aggregation + row softmax ----------------
// one node per 16-LANE GROUP (avg degree 17 -> ~full lane utilization).
// 256 threads = 16 nodes/block, grid = 2500.
__global__ __launch_bounds__(256) void k_agg2(
    const int* __restrict__ off, const int* __restrict__ csr_src,
    const float* __restrict__ h2pack, const float* __restrict__ a_d,
    const float* __restrict__ b2, float* __restrict__ out) {
  int t = threadIdx.x;
  int grp = t >> 4, gl = t & 15;
  int v = blockIdx.x * 16 + grp;
  int beg = off[v], end = off[v + 1];
  float adv = a_d[v];
  const float4* pk = (const float4*)h2pack;

  float sum = 0.f;
  float4 acc = {0.f, 0.f, 0.f, 0.f};
  for (int i = beg + gl; i < end; i += 16) {
    int s = csr_src[i];
    float4 r0 = pk[2 * s];          // h2[s]
    float4 r1 = pk[2 * s + 1];      // .x = a_s2[s], same 32B record
    float e = r1.x + adv;
    e = (e >= 0.f) ? e : 0.2f * e;
    float ex = __expf(e);
    sum += ex;
    acc.x = fmaf(ex, r0.x, acc.x);
    acc.y = fmaf(ex, r0.y, acc.y);
    acc.z = fmaf(ex, r0.z, acc.z);
    acc.w = fmaf(ex, r0.w, acc.w);
  }
  sum = red16(sum);
  acc.x = red16(acc.x);
  acc.y = red16(acc.y);
  acc.z = red16(acc.z);
  acc.w = red16(acc.w);

  if (gl == 0) {
    float invd = 1.f / (sum + 1e-16f);
    float o0 = acc.x * invd + b2[0];
    float o1 = acc.y * invd + b2[1];
    float o2 = acc.z * invd + b2[2];
    float o3 = acc.w * invd + b2[3];
    float mx = fmaxf(fmaxf(o0, o1), fmaxf(o2, o3));
    float e0 = __expf(o0 - mx), e1 = __expf(o1 - mx);
    float e2 = __expf(o2 - mx), e3 = __expf(o3 - mx);
    float s4 = e0 + e1 + e2 + e3;
    float4 r = {e0 / s4, e1 / s4, e2 / s4, e3 / s4};
    *(float4*)(out + (size_t)v * 4) = r;
  }
}

extern "C" void kernel_launch(void* const* d_in, const int* in_sizes, int n_in,
                              void* d_out, int out_size, void* d_ws, size_t ws_size,
                              hipStream_t stream) {
  const float* x   = (const float*)d_in[0];
  const int*   ei  = (const int*)d_in[1];   // [2, E]: row0 = src, row1 = dst
  const float* W1  = (const float*)d_in[3];
  const float* as1 = (const float*)d_in[4];
  const float* ad1 = (const float*)d_in[5];
  const float* b1  = (const float*)d_in[6];
  const float* W2  = (const float*)d_in[7];
  const float* as2 = (const float*)d_in[8];
  const float* ad2 = (const float*)d_in[9];
  const float* b2  = (const float*)d_in[10];
  float* out = (float*)d_out;

  char* w = (char*)d_ws;
  auto alloc = [&](size_t bytes) {
    char* p = w;
    w += (bytes + 255) & ~(size_t)255;
    return p;
  };
  int*   deg     = (int*)alloc((size_t)N_NODES * 4);
  int*   off     = (int*)alloc((size_t)(N_NODES + 1) * 4);
  int*   erank   = (int*)alloc((size_t)ET * 4);
  int*   csr_src = (int*)alloc((size_t)ET * 4);
  int*   blocksum= (int*)alloc((size_t)SCAN_BLOCKS * 4);
  __hip_bfloat16* h1b = (__hip_bfloat16*)alloc((size_t)N_NODES * 128 * 2);
  float* a_s1w   = (float*)alloc((size_t)N_NODES * 2 * 4);
  float* a_d1w   = (float*)alloc((size_t)N_NODES * 2 * 4);
  float* h2pack  = (float*)alloc((size_t)N_NODES * 8 * 4);   // 32B records
  float* a_d2w   = (float*)alloc((size_t)N_NODES * 4);

  hipMemsetAsync(deg, 0, (size_t)N_NODES * 4, stream);
  k_hist<<<(ET + 255) / 256, 256, 0, stream>>>(ei, deg, erank);
  k_scanA<<<SCAN_BLOCKS, 1024, 0, stream>>>(deg, blocksum);
  k_scanB<<<SCAN_BLOCKS, 1024, 0, stream>>>(deg, blocksum, off);
  k_fill<<<(ET + 255) / 256, 256, 0, stream>>>(ei, off, erank, csr_src);

  k_gemm1<<<N_NODES / 32, 256, 0, stream>>>(x, W1, as1, ad1, h1b, a_s1w, a_d1w);
  k_agg1<<<N_NODES / 4, 256, 0, stream>>>(off, csr_src, a_s1w, a_d1w, h1b, b1,
                                          W2, as2, ad2, h2pack, a_d2w);
  k_agg2<<<N_NODES / 16, 256, 0, stream>>>(off, csr_src, h2pack, a_d2w, b2, out);
}